// Round 11
// baseline (174.875 us; speedup 1.0000x reference)
//
#include <hip/hip_runtime.h>

// Problem constants: N=8, T=256, H=8, KQ=128, V=32
#define N_ 8
#define T_ 256
#define H_ 8
#define KQ_ 128
#define V_ 32
#define QT_ 8   // q rows per attn block

typedef float f32x4 __attribute__((ext_vector_type(4)));

// ---------------------------------------------------------------------------
// Phase 1 v4: tiled-GEMM projections, dst[n][h][d][t] transposed.
// v3 (R10): 28us with 66.5KB LDS -> 2 blocks/CU, latency-exposed.
// v4: W staged in two K=64 chunks (16KB, single-buffered) -> 49.5KB LDS
// -> 3 blocks/CU. Same FMA (2048/thr) and LDS-read counts; +2 barriers.
// grid: 1024 = proj(2)*n(8)*h(8)*tq(4 of 64t)*dh(2 of 64d), 256 thr
// ---------------------------------------------------------------------------
__global__ __launch_bounds__(256) void proj_kernel(
    const float* __restrict__ query, const float* __restrict__ key,
    const float* __restrict__ Wq, const float* __restrict__ bq,
    const float* __restrict__ Wk, const float* __restrict__ bk,
    float* __restrict__ hqT, float* __restrict__ hkT)
{
  int b = blockIdx.x;
  int dh = b & 1;
  int tq = (b >> 1) & 3;
  int h  = (b >> 3) & 7;
  int n  = (b >> 6) & 7;
  int proj = b >> 9;
  const float* src  = proj ? key : query;
  const float* W    = proj ? Wk  : Wq;
  const float* bias = proj ? bk  : bq;
  float* dst        = proj ? hkT : hqT;
  int t0 = tq * 64;
  int d0 = dh * 64;

  __shared__ float qs[64 * 132];   // q tile [t][j], full K, pad 132
  __shared__ float ws[64 * 64];    // W chunk [d][j-kc*64]

  {
    const float* qsrc = src + ((size_t)n * T_ + t0) * KQ_;
    for (int i = threadIdx.x; i < 64 * 32; i += 256) {   // float4 units
      int r = i >> 5, c4 = (i & 31) * 4;
      *(float4*)&qs[r * 132 + c4] = *(const float4*)&qsrc[(size_t)r * KQ_ + c4];
    }
  }

  int tl   = threadIdx.x & 31;      // lane -> t (coalesced stores)
  int dsub = threadIdx.x >> 5;      // 8 d's per thread, uniform per half-wave
  float acc0[8], acc1[8];
#pragma unroll
  for (int dd = 0; dd < 8; ++dd) { acc0[dd] = 0.f; acc1[dd] = 0.f; }

  const float* wsrc = W + (size_t)(h * KQ_ + d0) * KQ_;

  for (int kc = 0; kc < 2; ++kc) {
    if (kc) __syncthreads();        // prev chunk's compute done before restage
    {
      const float* wc = wsrc + kc * 64;
      for (int i = threadIdx.x; i < 64 * 16; i += 256) { // float4 units
        int r = i >> 4, c4 = (i & 15) * 4;
        *(float4*)&ws[r * 64 + c4] = *(const float4*)&wc[(size_t)r * KQ_ + c4];
      }
    }
    __syncthreads();                // ws (and qs on kc=0) visible

#pragma unroll 4
    for (int j0 = 0; j0 < 64; j0 += 4) {
      float4 q0 = *(const float4*)&qs[tl * 132 + kc * 64 + j0];
      float4 q1 = *(const float4*)&qs[(tl + 32) * 132 + kc * 64 + j0];
#pragma unroll
      for (int dd = 0; dd < 8; ++dd) {
        float4 w4 = *(const float4*)&ws[(dsub * 8 + dd) * 64 + j0]; // broadcast
        acc0[dd] = fmaf(q0.x, w4.x, acc0[dd]);
        acc0[dd] = fmaf(q0.y, w4.y, acc0[dd]);
        acc0[dd] = fmaf(q0.z, w4.z, acc0[dd]);
        acc0[dd] = fmaf(q0.w, w4.w, acc0[dd]);
        acc1[dd] = fmaf(q1.x, w4.x, acc1[dd]);
        acc1[dd] = fmaf(q1.y, w4.y, acc1[dd]);
        acc1[dd] = fmaf(q1.z, w4.z, acc1[dd]);
        acc1[dd] = fmaf(q1.w, w4.w, acc1[dd]);
      }
    }
  }

#pragma unroll
  for (int dd = 0; dd < 8; ++dd) {
    int d = d0 + dsub * 8 + dd;
    float bb = bias[h * KQ_ + d];
    size_t base = (((size_t)n * H_ + h) * KQ_ + d) * T_ + t0;
    dst[base + tl]      = acc0[dd] + bb;
    dst[base + tl + 32] = acc1[dd] + bb;
  }
}

// ---------------------------------------------------------------------------
// Phase 2a v2: scores -> softmax e -> denominators -> out_ws
// R11: red_s/red_o shrunk 16KB->8KB via shfl_xor(32) kg-pair pre-reduce
// (lane l <-> l^32 = same v, adjacent kg). LDS 29.5->21.6KB: 5->7 blocks/CU.
// grid: 2048 = n(8) * h(8) * qtile(32 of 8 q's), 256 threads
// ---------------------------------------------------------------------------
#define EPAD 9

__global__ __launch_bounds__(256) void attn_kernel(
    const float* __restrict__ hqT, const float* __restrict__ hkT,
    const int* __restrict__ mask, const float* __restrict__ value,
    float* __restrict__ e_ws, float* __restrict__ inv_ws,
    float* __restrict__ out_ws)
{
  const float SCALE = 0.08838834764831845f;   // 1/sqrt(128)
  int b = blockIdx.x;
  int q0 = (b & 31) * QT_;
  int h  = (b >> 5) & 7;
  int n  = b >> 8;
  int t  = threadIdx.x;
  int row0 = (n * H_ + h) * T_ + q0;

  __shared__ float hq_s[KQ_ * 8];      // 4KB
  __shared__ float e_s[T_ * EPAD];     // 9.2KB
  __shared__ float wred[4 * 8];
  __shared__ float red_s[4 * 8 * 32];  // 4KB (wave partials)
  __shared__ float red_o[4 * 8 * 32];  // 4KB

  const float* hqbase = hqT + ((size_t)n * H_ + h) * KQ_ * T_;
  const float* hkbase = hkT + ((size_t)n * H_ + h) * KQ_ * T_;

  {
    int qq = t & 7, j0 = t >> 3;
#pragma unroll
    for (int rep = 0; rep < 4; ++rep) {
      int j = j0 + rep * 32;
      hq_s[j * 8 + qq] = hqbase[(size_t)j * T_ + q0 + qq];
    }
  }
  __syncthreads();

  float acc[8];
#pragma unroll
  for (int qq = 0; qq < 8; ++qq) acc[qq] = 0.f;
#pragma unroll 4
  for (int j = 0; j < KQ_; ++j) {
    float hk = hkbase[(size_t)j * T_ + t];
    float4 a0 = *(const float4*)&hq_s[j * 8];
    float4 a1 = *(const float4*)&hq_s[j * 8 + 4];
    acc[0] = fmaf(a0.x, hk, acc[0]);
    acc[1] = fmaf(a0.y, hk, acc[1]);
    acc[2] = fmaf(a0.z, hk, acc[2]);
    acc[3] = fmaf(a0.w, hk, acc[3]);
    acc[4] = fmaf(a1.x, hk, acc[4]);
    acc[5] = fmaf(a1.y, hk, acc[5]);
    acc[6] = fmaf(a1.z, hk, acc[6]);
    acc[7] = fmaf(a1.w, hk, acc[7]);
  }
#pragma unroll
  for (int qq = 0; qq < 8; ++qq) acc[qq] *= SCALE;

  float mloc[8];
#pragma unroll
  for (int qq = 0; qq < 8; ++qq) {
    float m = acc[qq];
    for (int off = 32; off >= 1; off >>= 1)
      m = fmaxf(m, __shfl_xor(m, off, 64));
    mloc[qq] = m;
  }
  if ((t & 63) == 0) {
    int w = t >> 6;
#pragma unroll
    for (int qq = 0; qq < 8; ++qq) wred[w * 8 + qq] = mloc[qq];
  }
  __syncthreads();
  {
    float ev[8];
#pragma unroll
    for (int qq = 0; qq < 8; ++qq) {
      float mx = fmaxf(fmaxf(wred[0*8+qq], wred[1*8+qq]),
                       fmaxf(wred[2*8+qq], wred[3*8+qq]));
      ev[qq] = __expf(acc[qq] - mx);
    }
    *(float4*)&e_s[t * EPAD]     = make_float4(ev[0], ev[1], ev[2], ev[3]);
    *(float4*)&e_s[t * EPAD + 4] = make_float4(ev[4], ev[5], ev[6], ev[7]);
#pragma unroll
    for (int qq = 0; qq < 8; ++qq)
      e_ws[(size_t)(row0 + qq) * T_ + t] = ev[qq];
  }
  __syncthreads();

  const int*   mrow = mask  + (size_t)n * T_ * V_;
  const float* vrow = value + (size_t)n * T_ * V_;
  int v = t & 31, kg = t >> 5;
  float s8[8], o8[8];
#pragma unroll
  for (int qq = 0; qq < 8; ++qq) { s8[qq] = 0.f; o8[qq] = 0.f; }
  for (int i = 0; i < 32; ++i) {
    int k = kg * 32 + i;
    float mf = (float)mrow[k * V_ + v];
    float vv = vrow[k * V_ + v];
    float4 e0 = *(const float4*)&e_s[k * EPAD];      // broadcast reads
    float4 e1 = *(const float4*)&e_s[k * EPAD + 4];
    float p;
    p = e0.x * mf; s8[0] += p; o8[0] = fmaf(p, vv, o8[0]);
    p = e0.y * mf; s8[1] += p; o8[1] = fmaf(p, vv, o8[1]);
    p = e0.z * mf; s8[2] += p; o8[2] = fmaf(p, vv, o8[2]);
    p = e0.w * mf; s8[3] += p; o8[3] = fmaf(p, vv, o8[3]);
    p = e1.x * mf; s8[4] += p; o8[4] = fmaf(p, vv, o8[4]);
    p = e1.y * mf; s8[5] += p; o8[5] = fmaf(p, vv, o8[5]);
    p = e1.z * mf; s8[6] += p; o8[6] = fmaf(p, vv, o8[6]);
    p = e1.w * mf; s8[7] += p; o8[7] = fmaf(p, vv, o8[7]);
  }
  // kg-pair pre-reduce: lane l <-> l^32 holds same v, partner kg
#pragma unroll
  for (int qq = 0; qq < 8; ++qq) {
    s8[qq] += __shfl_xor(s8[qq], 32, 64);
    o8[qq] += __shfl_xor(o8[qq], 32, 64);
  }
  {
    int w = t >> 6;
    if ((t & 63) < 32) {
#pragma unroll
      for (int qq = 0; qq < 8; ++qq) {
        red_s[(w * 8 + qq) * 32 + v] = s8[qq];
        red_o[(w * 8 + qq) * 32 + v] = o8[qq];
      }
    }
  }
  __syncthreads();
  {
    int qq = t >> 5, v2 = t & 31;
    float s = 0.f, o = 0.f;
#pragma unroll
    for (int w2 = 0; w2 < 4; ++w2) {
      s += red_s[(w2 * 8 + qq) * 32 + v2];
      o += red_o[(w2 * 8 + qq) * 32 + v2];
    }
    float inv = 1.0f / s;
    inv_ws[(size_t)(row0 + qq) * V_ + v2] = inv;
    out_ws[(((size_t)n * T_ + q0 + qq) * H_ + h) * V_ + v2] = o * inv;
  }
}

// ---------------------------------------------------------------------------
// Phase 2b: streaming p_attn writes. Measured ~76us ≈ write roofline. FINAL.
// ---------------------------------------------------------------------------
__global__ __launch_bounds__(256) void pwrite_kernel(
    const float* __restrict__ e_ws, const float* __restrict__ inv_ws,
    const int* __restrict__ mask, float* __restrict__ p_out)
{
  int b = blockIdx.x;
  int row0 = b * 4;
  int n = row0 >> 11;
  const int* mrow = mask + (size_t)n * T_ * V_;
  int t = threadIdx.x;
  int v0 = (t & 7) * 4;
  int kbase = t >> 3;

  float4 iv[4];
  const float* erow[4];
  f32x4* dst4[4];
#pragma unroll
  for (int qq = 0; qq < 4; ++qq) {
    int row = row0 + qq;
    iv[qq]   = *(const float4*)&inv_ws[(size_t)row * V_ + v0];
    erow[qq] = e_ws + (size_t)row * T_;
    dst4[qq] = (f32x4*)p_out + (size_t)row * 2048;
  }

#pragma unroll
  for (int rep = 0; rep < 8; ++rep) {
    int k = rep * 32 + kbase;
    const int4 m4 = *(const int4*)&mrow[k * V_ + v0];
    float fx = (float)m4.x, fy = (float)m4.y, fz = (float)m4.z, fw = (float)m4.w;
#pragma unroll
    for (int qq = 0; qq < 4; ++qq) {
      float e = erow[qq][k];
      f32x4 pv;
      pv.x = e * fx * iv[qq].x;
      pv.y = e * fy * iv[qq].y;
      pv.z = e * fz * iv[qq].z;
      pv.w = e * fw * iv[qq].w;
      __builtin_nontemporal_store(pv, &dst4[qq][rep * 256 + t]);
    }
  }
}

// ---------------------------------------------------------------------------
// Phase 3 v2 (frozen from R8)
// ---------------------------------------------------------------------------
__global__ __launch_bounds__(256) void outproj_kernel(
    const float* __restrict__ out_ws, const float* __restrict__ Wo,
    const float* __restrict__ bo, float* __restrict__ out_rep)
{
  __shared__ float wot[256 * 33];
  __shared__ float rows_s[4 * 256];
  __shared__ float red[4 * 32];
  int r0 = blockIdx.x * 4;
  for (int i = threadIdx.x; i < 32 * 256; i += 256) {
    int o = i >> 8, c = i & 255;
    wot[c * 33 + o] = Wo[i];
  }
  for (int i = threadIdx.x; i < 4 * 256; i += 256)
    rows_s[i] = out_ws[(size_t)r0 * 256 + i];
  __syncthreads();
  int o  = threadIdx.x & 31;
  int rr = (threadIdx.x >> 5) & 3;
  int kh = threadIdx.x >> 7;
  int cb = kh * 128;
  float acc = 0.f;
#pragma unroll 4
  for (int c = 0; c < 128; ++c)
    acc = fmaf(rows_s[rr * 256 + cb + c], wot[(cb + c) * 33 + o], acc);
  if (kh == 1) red[rr * 32 + o] = acc;
  __syncthreads();
  if (kh == 0)
    out_rep[(size_t)(r0 + rr) * 32 + o] = acc + red[rr * 32 + o] + bo[o];
}

// ---------------------------------------------------------------------------
extern "C" void kernel_launch(void* const* d_in, const int* in_sizes, int n_in,
                              void* d_out, int out_size, void* d_ws, size_t ws_size,
                              hipStream_t stream) {
  const float* value = (const float*)d_in[0];
  const float* key   = (const float*)d_in[1];
  const float* query = (const float*)d_in[2];
  const int*   mask  = (const int*)d_in[3];
  const float* Wq = (const float*)d_in[4];
  const float* bq = (const float*)d_in[5];
  const float* Wk = (const float*)d_in[6];
  const float* bk = (const float*)d_in[7];
  const float* Wo = (const float*)d_in[8];
  const float* bo = (const float*)d_in[9];

  float* out_rep = (float*)d_out;
  float* p_out   = (float*)d_out + (size_t)N_ * T_ * V_;

  float* hqT    = (float*)d_ws;
  float* hkT    = hqT    + (size_t)N_ * H_ * KQ_ * T_;
  float* out_ws = hkT    + (size_t)N_ * H_ * KQ_ * T_;
  float* e_ws   = out_ws + (size_t)N_ * T_ * H_ * V_;
  float* inv_ws = e_ws   + (size_t)N_ * H_ * T_ * T_;

  hipLaunchKernelGGL(proj_kernel, dim3(1024), dim3(256), 0, stream,
                     query, key, Wq, bq, Wk, bk, hqT, hkT);
  hipLaunchKernelGGL(attn_kernel, dim3(2048), dim3(256), 0, stream,
                     hqT, hkT, mask, value, e_ws, inv_ws, out_ws);
  hipLaunchKernelGGL(pwrite_kernel, dim3(4096), dim3(256), 0, stream,
                     e_ws, inv_ws, mask, p_out);
  hipLaunchKernelGGL(outproj_kernel, dim3(512), dim3(256), 0, stream,
                     out_ws, Wo, bo, out_rep);
}

// Round 12
// 170.397 us; speedup vs baseline: 1.0263x; 1.0263x over previous
//
#include <hip/hip_runtime.h>

// Problem constants: N=8, T=256, H=8, KQ=128, V=32
#define N_ 8
#define T_ 256
#define H_ 8
#define KQ_ 128
#define V_ 32

typedef float f32x4 __attribute__((ext_vector_type(4)));

// ---------------------------------------------------------------------------
// Phase 1 v5: tiled-GEMM projections, dst[n][h][d][t] transposed.
// R11 diagnosis: v3/v4 LDS-instruction-bound (~3.1k b128/CU = 15us) with only
// 6.4 FMA per b128. v5: 8t x 8d per thread -> 16 b128 per 256 FMA (16/b128).
// Tile 256t x 64d, K chunked x32 (qs 36.9KB + ws 9.2KB = 46KB LDS).
// grid: 256 = proj(2)*n(8)*h(8)*dh(2), 256 thr (1 block/CU, 4 waves)
// ---------------------------------------------------------------------------
__global__ __launch_bounds__(256) void proj_kernel(
    const float* __restrict__ query, const float* __restrict__ key,
    const float* __restrict__ Wq, const float* __restrict__ bq,
    const float* __restrict__ Wk, const float* __restrict__ bk,
    float* __restrict__ hqT, float* __restrict__ hkT)
{
  int b = blockIdx.x;
  int dh = b & 1;
  int h  = (b >> 1) & 7;
  int n  = (b >> 4) & 7;
  int proj = (b >> 7) & 1;
  const float* src  = proj ? key : query;
  const float* W    = proj ? Wk  : Wq;
  const float* bias = proj ? bk  : bq;
  float* dst        = proj ? hkT : hqT;
  int d0 = dh * 64;

  __shared__ float qs[256 * 36];   // [t][j-chunk], pad 36
  __shared__ float ws[64 * 36];    // [d][j-chunk], pad 36

  int tl   = threadIdx.x & 31;     // t-low (lane): coalesced stores
  int dsub = threadIdx.x >> 5;     // 8 d's per thread
  const float* qsrc = src + (size_t)n * T_ * KQ_;
  const float* wsrc = W + (size_t)(h * KQ_ + d0) * KQ_;

  float acc[8][8];                 // [it][dd], all static indices
#pragma unroll
  for (int it = 0; it < 8; ++it)
#pragma unroll
    for (int dd = 0; dd < 8; ++dd) acc[it][dd] = 0.f;

  for (int kc = 0; kc < 4; ++kc) {
    if (kc) __syncthreads();
    // stage q chunk: 256 rows x 8 float4
    {
      int r = threadIdx.x >> 3, c4 = (threadIdx.x & 7) * 4;
#pragma unroll
      for (int rep = 0; rep < 8; ++rep) {
        int row = r + rep * 32;
        *(float4*)&qs[row * 36 + c4] =
            *(const float4*)&qsrc[(size_t)row * KQ_ + kc * 32 + c4];
      }
      // stage W chunk: 64 rows x 8 float4
#pragma unroll
      for (int rep = 0; rep < 2; ++rep) {
        int row = r + rep * 32;
        *(float4*)&ws[row * 36 + c4] =
            *(const float4*)&wsrc[(size_t)row * KQ_ + kc * 32 + c4];
      }
    }
    __syncthreads();

#pragma unroll 2
    for (int j0 = 0; j0 < 32; j0 += 4) {
      float4 qv[8];
#pragma unroll
      for (int it = 0; it < 8; ++it)
        qv[it] = *(const float4*)&qs[(tl + 32 * it) * 36 + j0];
#pragma unroll
      for (int dd = 0; dd < 8; ++dd) {
        float4 w4 = *(const float4*)&ws[(dsub * 8 + dd) * 36 + j0]; // broadcast
#pragma unroll
        for (int it = 0; it < 8; ++it) {
          acc[it][dd] = fmaf(qv[it].x, w4.x, acc[it][dd]);
          acc[it][dd] = fmaf(qv[it].y, w4.y, acc[it][dd]);
          acc[it][dd] = fmaf(qv[it].z, w4.z, acc[it][dd]);
          acc[it][dd] = fmaf(qv[it].w, w4.w, acc[it][dd]);
        }
      }
    }
  }

#pragma unroll
  for (int dd = 0; dd < 8; ++dd) {
    int d = d0 + dsub * 8 + dd;
    float bb = bias[h * KQ_ + d];
    size_t base = (((size_t)n * H_ + h) * KQ_ + d) * T_;
#pragma unroll
    for (int it = 0; it < 8; ++it)
      dst[base + it * 32 + tl] = acc[it][dd] + bb;
  }
}

// ---------------------------------------------------------------------------
// Phase 2a v3: one WAVE per 8-q tile (wave-synchronous, Tk=4 k's/lane).
// R11 diagnosis: v1/v2 LDS-instr-bound (score re-read hq 2x per j for only
// 8 FMA). v3: lane k=l+64i (i<4) -> 2 b128 per j feed 32 FMA; denominator
// half-wave k-split + shfl_xor(32) halves e_s re-reads. LDS 14.2KB/block.
// grid: 2048 = n(8)*h(8)*qtile(32), 64 threads.
// ---------------------------------------------------------------------------
__global__ __launch_bounds__(64) void attn_kernel(
    const float* __restrict__ hqT, const float* __restrict__ hkT,
    const int* __restrict__ mask, const float* __restrict__ value,
    float* __restrict__ e_ws, float* __restrict__ inv_ws,
    float* __restrict__ out_ws)
{
  const float SCALE = 0.08838834764831845f;   // 1/sqrt(128)
  int b = blockIdx.x;
  int q0 = (b & 31) * 8;
  int h  = (b >> 5) & 7;
  int n  = b >> 8;
  int l  = threadIdx.x;                        // 0..63, single wave
  int row0 = (n * H_ + h) * T_ + q0;

  __shared__ float hq_s[KQ_ * 12];   // [j][qq] pad 12 -> 6.1KB
  __shared__ float e_s[T_ * 8];      // [k][qq] 8KB

  const float* hqbase = hqT + ((size_t)n * H_ + h) * KQ_ * T_;
  const float* hkbase = hkT + ((size_t)n * H_ + h) * KQ_ * T_;

  // stage hq: 128j x 8q
#pragma unroll
  for (int rep = 0; rep < 16; ++rep) {
    int i = l + 64 * rep;
    int j = i >> 3, qq = i & 7;
    hq_s[j * 12 + qq] = hqbase[(size_t)j * T_ + q0 + qq];
  }
  __syncthreads();

  // scores: lane l covers k = l + 64i, i=0..3
  float acc[4][8];
#pragma unroll
  for (int i = 0; i < 4; ++i)
#pragma unroll
    for (int qq = 0; qq < 8; ++qq) acc[i][qq] = 0.f;

#pragma unroll 4
  for (int j = 0; j < KQ_; ++j) {
    float hk0 = hkbase[(size_t)j * T_ + l];
    float hk1 = hkbase[(size_t)j * T_ + l + 64];
    float hk2 = hkbase[(size_t)j * T_ + l + 128];
    float hk3 = hkbase[(size_t)j * T_ + l + 192];
    float4 a0 = *(const float4*)&hq_s[j * 12];       // wave-uniform broadcast
    float4 a1 = *(const float4*)&hq_s[j * 12 + 4];
    acc[0][0] = fmaf(a0.x, hk0, acc[0][0]); acc[0][1] = fmaf(a0.y, hk0, acc[0][1]);
    acc[0][2] = fmaf(a0.z, hk0, acc[0][2]); acc[0][3] = fmaf(a0.w, hk0, acc[0][3]);
    acc[0][4] = fmaf(a1.x, hk0, acc[0][4]); acc[0][5] = fmaf(a1.y, hk0, acc[0][5]);
    acc[0][6] = fmaf(a1.z, hk0, acc[0][6]); acc[0][7] = fmaf(a1.w, hk0, acc[0][7]);
    acc[1][0] = fmaf(a0.x, hk1, acc[1][0]); acc[1][1] = fmaf(a0.y, hk1, acc[1][1]);
    acc[1][2] = fmaf(a0.z, hk1, acc[1][2]); acc[1][3] = fmaf(a0.w, hk1, acc[1][3]);
    acc[1][4] = fmaf(a1.x, hk1, acc[1][4]); acc[1][5] = fmaf(a1.y, hk1, acc[1][5]);
    acc[1][6] = fmaf(a1.z, hk1, acc[1][6]); acc[1][7] = fmaf(a1.w, hk1, acc[1][7]);
    acc[2][0] = fmaf(a0.x, hk2, acc[2][0]); acc[2][1] = fmaf(a0.y, hk2, acc[2][1]);
    acc[2][2] = fmaf(a0.z, hk2, acc[2][2]); acc[2][3] = fmaf(a0.w, hk2, acc[2][3]);
    acc[2][4] = fmaf(a1.x, hk2, acc[2][4]); acc[2][5] = fmaf(a1.y, hk2, acc[2][5]);
    acc[2][6] = fmaf(a1.z, hk2, acc[2][6]); acc[2][7] = fmaf(a1.w, hk2, acc[2][7]);
    acc[3][0] = fmaf(a0.x, hk3, acc[3][0]); acc[3][1] = fmaf(a0.y, hk3, acc[3][1]);
    acc[3][2] = fmaf(a0.z, hk3, acc[3][2]); acc[3][3] = fmaf(a0.w, hk3, acc[3][3]);
    acc[3][4] = fmaf(a1.x, hk3, acc[3][4]); acc[3][5] = fmaf(a1.y, hk3, acc[3][5]);
    acc[3][6] = fmaf(a1.z, hk3, acc[3][6]); acc[3][7] = fmaf(a1.w, hk3, acc[3][7]);
  }

  // softmax numerators
  float ev[4][8];
  {
#pragma unroll
    for (int qq = 0; qq < 8; ++qq) {
      float m = fmaxf(fmaxf(acc[0][qq] * SCALE, acc[1][qq] * SCALE),
                      fmaxf(acc[2][qq] * SCALE, acc[3][qq] * SCALE));
      for (int off = 32; off >= 1; off >>= 1)
        m = fmaxf(m, __shfl_xor(m, off, 64));
#pragma unroll
      for (int i = 0; i < 4; ++i)
        ev[i][qq] = __expf(acc[i][qq] * SCALE - m);
    }
  }
  // spill e to ws ([row][k], coalesced) and LDS ([k][qq])
#pragma unroll
  for (int i = 0; i < 4; ++i) {
#pragma unroll
    for (int qq = 0; qq < 8; ++qq)
      e_ws[(size_t)(row0 + qq) * T_ + l + 64 * i] = ev[i][qq];
    int k = l + 64 * i;
    *(f32x4*)&e_s[k * 8]     = f32x4{ev[i][0], ev[i][1], ev[i][2], ev[i][3]};
    *(f32x4*)&e_s[k * 8 + 4] = f32x4{ev[i][4], ev[i][5], ev[i][6], ev[i][7]};
  }
  __syncthreads();

  // denominators + PV: v = l&31, half-wave splits k; shfl_xor(32) combines
  const int*   mrow = mask  + (size_t)n * T_ * V_;
  const float* vrow = value + (size_t)n * T_ * V_;
  int v = l & 31, kh = l >> 5;
  float s8[8], o8[8];
#pragma unroll
  for (int qq = 0; qq < 8; ++qq) { s8[qq] = 0.f; o8[qq] = 0.f; }
#pragma unroll 4
  for (int i = 0; i < 128; ++i) {
    int k = kh * 128 + i;
    float mf = (float)mrow[k * V_ + v];
    float vv = vrow[k * V_ + v];
    float4 e0 = *(const float4*)&e_s[k * 8];       // uniform per half-wave
    float4 e1 = *(const float4*)&e_s[k * 8 + 4];
    float p;
    p = e0.x * mf; s8[0] += p; o8[0] = fmaf(p, vv, o8[0]);
    p = e0.y * mf; s8[1] += p; o8[1] = fmaf(p, vv, o8[1]);
    p = e0.z * mf; s8[2] += p; o8[2] = fmaf(p, vv, o8[2]);
    p = e0.w * mf; s8[3] += p; o8[3] = fmaf(p, vv, o8[3]);
    p = e1.x * mf; s8[4] += p; o8[4] = fmaf(p, vv, o8[4]);
    p = e1.y * mf; s8[5] += p; o8[5] = fmaf(p, vv, o8[5]);
    p = e1.z * mf; s8[6] += p; o8[6] = fmaf(p, vv, o8[6]);
    p = e1.w * mf; s8[7] += p; o8[7] = fmaf(p, vv, o8[7]);
  }
#pragma unroll
  for (int qq = 0; qq < 8; ++qq) {
    s8[qq] += __shfl_xor(s8[qq], 32, 64);
    o8[qq] += __shfl_xor(o8[qq], 32, 64);
  }
  if (kh == 0) {
#pragma unroll
    for (int qq = 0; qq < 8; ++qq) {
      float inv = 1.0f / s8[qq];
      inv_ws[(size_t)(row0 + qq) * V_ + v] = inv;
      out_ws[(((size_t)n * T_ + q0 + qq) * H_ + h) * V_ + v] = o8[qq] * inv;
    }
  }
}

// ---------------------------------------------------------------------------
// Phase 2b: streaming p_attn writes. Measured ~76us ≈ write roofline. FINAL.
// ---------------------------------------------------------------------------
__global__ __launch_bounds__(256) void pwrite_kernel(
    const float* __restrict__ e_ws, const float* __restrict__ inv_ws,
    const int* __restrict__ mask, float* __restrict__ p_out)
{
  int b = blockIdx.x;
  int row0 = b * 4;
  int n = row0 >> 11;
  const int* mrow = mask + (size_t)n * T_ * V_;
  int t = threadIdx.x;
  int v0 = (t & 7) * 4;
  int kbase = t >> 3;

  float4 iv[4];
  const float* erow[4];
  f32x4* dst4[4];
#pragma unroll
  for (int qq = 0; qq < 4; ++qq) {
    int row = row0 + qq;
    iv[qq]   = *(const float4*)&inv_ws[(size_t)row * V_ + v0];
    erow[qq] = e_ws + (size_t)row * T_;
    dst4[qq] = (f32x4*)p_out + (size_t)row * 2048;
  }

#pragma unroll
  for (int rep = 0; rep < 8; ++rep) {
    int k = rep * 32 + kbase;
    const int4 m4 = *(const int4*)&mrow[k * V_ + v0];
    float fx = (float)m4.x, fy = (float)m4.y, fz = (float)m4.z, fw = (float)m4.w;
#pragma unroll
    for (int qq = 0; qq < 4; ++qq) {
      float e = erow[qq][k];
      f32x4 pv;
      pv.x = e * fx * iv[qq].x;
      pv.y = e * fy * iv[qq].y;
      pv.z = e * fz * iv[qq].z;
      pv.w = e * fw * iv[qq].w;
      __builtin_nontemporal_store(pv, &dst4[qq][rep * 256 + t]);
    }
  }
}

// ---------------------------------------------------------------------------
// Phase 3 v2 (frozen from R8)
// ---------------------------------------------------------------------------
__global__ __launch_bounds__(256) void outproj_kernel(
    const float* __restrict__ out_ws, const float* __restrict__ Wo,
    const float* __restrict__ bo, float* __restrict__ out_rep)
{
  __shared__ float wot[256 * 33];
  __shared__ float rows_s[4 * 256];
  __shared__ float red[4 * 32];
  int r0 = blockIdx.x * 4;
  for (int i = threadIdx.x; i < 32 * 256; i += 256) {
    int o = i >> 8, c = i & 255;
    wot[c * 33 + o] = Wo[i];
  }
  for (int i = threadIdx.x; i < 4 * 256; i += 256)
    rows_s[i] = out_ws[(size_t)r0 * 256 + i];
  __syncthreads();
  int o  = threadIdx.x & 31;
  int rr = (threadIdx.x >> 5) & 3;
  int kh = threadIdx.x >> 7;
  int cb = kh * 128;
  float acc = 0.f;
#pragma unroll 4
  for (int c = 0; c < 128; ++c)
    acc = fmaf(rows_s[rr * 256 + cb + c], wot[(cb + c) * 33 + o], acc);
  if (kh == 1) red[rr * 32 + o] = acc;
  __syncthreads();
  if (kh == 0)
    out_rep[(size_t)(r0 + rr) * 32 + o] = acc + red[rr * 32 + o] + bo[o];
}

// ---------------------------------------------------------------------------
extern "C" void kernel_launch(void* const* d_in, const int* in_sizes, int n_in,
                              void* d_out, int out_size, void* d_ws, size_t ws_size,
                              hipStream_t stream) {
  const float* value = (const float*)d_in[0];
  const float* key   = (const float*)d_in[1];
  const float* query = (const float*)d_in[2];
  const int*   mask  = (const int*)d_in[3];
  const float* Wq = (const float*)d_in[4];
  const float* bq = (const float*)d_in[5];
  const float* Wk = (const float*)d_in[6];
  const float* bk = (const float*)d_in[7];
  const float* Wo = (const float*)d_in[8];
  const float* bo = (const float*)d_in[9];

  float* out_rep = (float*)d_out;
  float* p_out   = (float*)d_out + (size_t)N_ * T_ * V_;

  float* hqT    = (float*)d_ws;
  float* hkT    = hqT    + (size_t)N_ * H_ * KQ_ * T_;
  float* out_ws = hkT    + (size_t)N_ * H_ * KQ_ * T_;
  float* e_ws   = out_ws + (size_t)N_ * T_ * H_ * V_;
  float* inv_ws = e_ws   + (size_t)N_ * H_ * T_ * T_;

  hipLaunchKernelGGL(proj_kernel, dim3(256), dim3(256), 0, stream,
                     query, key, Wq, bq, Wk, bk, hqT, hkT);
  hipLaunchKernelGGL(attn_kernel, dim3(2048), dim3(64), 0, stream,
                     hqT, hkT, mask, value, e_ws, inv_ws, out_ws);
  hipLaunchKernelGGL(pwrite_kernel, dim3(4096), dim3(256), 0, stream,
                     e_ws, inv_ws, mask, p_out);
  hipLaunchKernelGGL(outproj_kernel, dim3(512), dim3(256), 0, stream,
                     out_ws, Wo, bo, out_rep);
}

// Round 13
// 157.950 us; speedup vs baseline: 1.1072x; 1.0788x over previous
//
#include <hip/hip_runtime.h>

// Problem constants: N=8, T=256, H=8, KQ=128, V=32
#define N_ 8
#define T_ 256
#define H_ 8
#define KQ_ 128
#define V_ 32

typedef float f32x4 __attribute__((ext_vector_type(4)));

// ---------------------------------------------------------------------------
// Phase 1 v5 (frozen from R12): tiled-GEMM projections, dst[n][h][d][t].
// grid: 256 = proj(2)*n(8)*h(8)*dh(2), 256 thr
// ---------------------------------------------------------------------------
__global__ __launch_bounds__(256) void proj_kernel(
    const float* __restrict__ query, const float* __restrict__ key,
    const float* __restrict__ Wq, const float* __restrict__ bq,
    const float* __restrict__ Wk, const float* __restrict__ bk,
    float* __restrict__ hqT, float* __restrict__ hkT)
{
  int b = blockIdx.x;
  int dh = b & 1;
  int h  = (b >> 1) & 7;
  int n  = (b >> 4) & 7;
  int proj = (b >> 7) & 1;
  const float* src  = proj ? key : query;
  const float* W    = proj ? Wk  : Wq;
  const float* bias = proj ? bk  : bq;
  float* dst        = proj ? hkT : hqT;
  int d0 = dh * 64;

  __shared__ float qs[256 * 36];
  __shared__ float ws[64 * 36];

  int tl   = threadIdx.x & 31;
  int dsub = threadIdx.x >> 5;
  const float* qsrc = src + (size_t)n * T_ * KQ_;
  const float* wsrc = W + (size_t)(h * KQ_ + d0) * KQ_;

  float acc[8][8];
#pragma unroll
  for (int it = 0; it < 8; ++it)
#pragma unroll
    for (int dd = 0; dd < 8; ++dd) acc[it][dd] = 0.f;

  for (int kc = 0; kc < 4; ++kc) {
    if (kc) __syncthreads();
    {
      int r = threadIdx.x >> 3, c4 = (threadIdx.x & 7) * 4;
#pragma unroll
      for (int rep = 0; rep < 8; ++rep) {
        int row = r + rep * 32;
        *(float4*)&qs[row * 36 + c4] =
            *(const float4*)&qsrc[(size_t)row * KQ_ + kc * 32 + c4];
      }
#pragma unroll
      for (int rep = 0; rep < 2; ++rep) {
        int row = r + rep * 32;
        *(float4*)&ws[row * 36 + c4] =
            *(const float4*)&wsrc[(size_t)row * KQ_ + kc * 32 + c4];
      }
    }
    __syncthreads();

#pragma unroll 2
    for (int j0 = 0; j0 < 32; j0 += 4) {
      float4 qv[8];
#pragma unroll
      for (int it = 0; it < 8; ++it)
        qv[it] = *(const float4*)&qs[(tl + 32 * it) * 36 + j0];
#pragma unroll
      for (int dd = 0; dd < 8; ++dd) {
        float4 w4 = *(const float4*)&ws[(dsub * 8 + dd) * 36 + j0];
#pragma unroll
        for (int it = 0; it < 8; ++it) {
          acc[it][dd] = fmaf(qv[it].x, w4.x, acc[it][dd]);
          acc[it][dd] = fmaf(qv[it].y, w4.y, acc[it][dd]);
          acc[it][dd] = fmaf(qv[it].z, w4.z, acc[it][dd]);
          acc[it][dd] = fmaf(qv[it].w, w4.w, acc[it][dd]);
        }
      }
    }
  }

#pragma unroll
  for (int dd = 0; dd < 8; ++dd) {
    int d = d0 + dsub * 8 + dd;
    float bb = bias[h * KQ_ + d];
    size_t base = (((size_t)n * H_ + h) * KQ_ + d) * T_;
#pragma unroll
    for (int it = 0; it < 8; ++it)
      dst[base + it * 32 + tl] = acc[it][dd] + bb;
  }
}

// ---------------------------------------------------------------------------
// Phase 2 FUSED (R13): scores -> softmax -> denominators/PV -> direct p_attn
// NT stores. Removes pwrite kernel + the 36MB e_ws/inv_ws round-trip; each
// block streams its own 8 rows (64KB) so later blocks' compute overlaps
// earlier blocks' stores. One wave per 8-q tile; LDS 15.2KB.
// grid: 2048 = n(8)*h(8)*qtile(32), 64 threads.
// ---------------------------------------------------------------------------
__global__ __launch_bounds__(64) void attn_kernel(
    const float* __restrict__ hqT, const float* __restrict__ hkT,
    const int* __restrict__ mask, const float* __restrict__ value,
    float* __restrict__ p_out, float* __restrict__ out_ws)
{
  const float SCALE = 0.08838834764831845f;   // 1/sqrt(128)
  int b = blockIdx.x;
  int q0 = (b & 31) * 8;
  int h  = (b >> 5) & 7;
  int n  = b >> 8;
  int l  = threadIdx.x;                        // 0..63, single wave
  int row0 = (n * H_ + h) * T_ + q0;

  __shared__ float hq_s[KQ_ * 12];   // [j][qq] pad 12
  __shared__ float e_s[T_ * 8];      // [k][qq]
  __shared__ float inv_s[8 * 32];    // [qq][v]

  const float* hqbase = hqT + ((size_t)n * H_ + h) * KQ_ * T_;
  const float* hkbase = hkT + ((size_t)n * H_ + h) * KQ_ * T_;

  // stage hq: 128j x 8q
#pragma unroll
  for (int rep = 0; rep < 16; ++rep) {
    int i = l + 64 * rep;
    int j = i >> 3, qq = i & 7;
    hq_s[j * 12 + qq] = hqbase[(size_t)j * T_ + q0 + qq];
  }
  __syncthreads();

  // scores: lane l covers k = l + 64i, i=0..3
  float acc[4][8];
#pragma unroll
  for (int i = 0; i < 4; ++i)
#pragma unroll
    for (int qq = 0; qq < 8; ++qq) acc[i][qq] = 0.f;

#pragma unroll 4
  for (int j = 0; j < KQ_; ++j) {
    float hk0 = hkbase[(size_t)j * T_ + l];
    float hk1 = hkbase[(size_t)j * T_ + l + 64];
    float hk2 = hkbase[(size_t)j * T_ + l + 128];
    float hk3 = hkbase[(size_t)j * T_ + l + 192];
    float4 a0 = *(const float4*)&hq_s[j * 12];       // wave-uniform broadcast
    float4 a1 = *(const float4*)&hq_s[j * 12 + 4];
    acc[0][0] = fmaf(a0.x, hk0, acc[0][0]); acc[0][1] = fmaf(a0.y, hk0, acc[0][1]);
    acc[0][2] = fmaf(a0.z, hk0, acc[0][2]); acc[0][3] = fmaf(a0.w, hk0, acc[0][3]);
    acc[0][4] = fmaf(a1.x, hk0, acc[0][4]); acc[0][5] = fmaf(a1.y, hk0, acc[0][5]);
    acc[0][6] = fmaf(a1.z, hk0, acc[0][6]); acc[0][7] = fmaf(a1.w, hk0, acc[0][7]);
    acc[1][0] = fmaf(a0.x, hk1, acc[1][0]); acc[1][1] = fmaf(a0.y, hk1, acc[1][1]);
    acc[1][2] = fmaf(a0.z, hk1, acc[1][2]); acc[1][3] = fmaf(a0.w, hk1, acc[1][3]);
    acc[1][4] = fmaf(a1.x, hk1, acc[1][4]); acc[1][5] = fmaf(a1.y, hk1, acc[1][5]);
    acc[1][6] = fmaf(a1.z, hk1, acc[1][6]); acc[1][7] = fmaf(a1.w, hk1, acc[1][7]);
    acc[2][0] = fmaf(a0.x, hk2, acc[2][0]); acc[2][1] = fmaf(a0.y, hk2, acc[2][1]);
    acc[2][2] = fmaf(a0.z, hk2, acc[2][2]); acc[2][3] = fmaf(a0.w, hk2, acc[2][3]);
    acc[2][4] = fmaf(a1.x, hk2, acc[2][4]); acc[2][5] = fmaf(a1.y, hk2, acc[2][5]);
    acc[2][6] = fmaf(a1.z, hk2, acc[2][6]); acc[2][7] = fmaf(a1.w, hk2, acc[2][7]);
    acc[3][0] = fmaf(a0.x, hk3, acc[3][0]); acc[3][1] = fmaf(a0.y, hk3, acc[3][1]);
    acc[3][2] = fmaf(a0.z, hk3, acc[3][2]); acc[3][3] = fmaf(a0.w, hk3, acc[3][3]);
    acc[3][4] = fmaf(a1.x, hk3, acc[3][4]); acc[3][5] = fmaf(a1.y, hk3, acc[3][5]);
    acc[3][6] = fmaf(a1.z, hk3, acc[3][6]); acc[3][7] = fmaf(a1.w, hk3, acc[3][7]);
  }

  // softmax numerators -> e_s (no global spill)
  {
#pragma unroll
    for (int qq = 0; qq < 8; ++qq) {
      float m = fmaxf(fmaxf(acc[0][qq] * SCALE, acc[1][qq] * SCALE),
                      fmaxf(acc[2][qq] * SCALE, acc[3][qq] * SCALE));
      for (int off = 32; off >= 1; off >>= 1)
        m = fmaxf(m, __shfl_xor(m, off, 64));
#pragma unroll
      for (int i = 0; i < 4; ++i)
        acc[i][qq] = __expf(acc[i][qq] * SCALE - m);   // acc now holds e
    }
  }
#pragma unroll
  for (int i = 0; i < 4; ++i) {
    int k = l + 64 * i;
    *(f32x4*)&e_s[k * 8]     = f32x4{acc[i][0], acc[i][1], acc[i][2], acc[i][3]};
    *(f32x4*)&e_s[k * 8 + 4] = f32x4{acc[i][4], acc[i][5], acc[i][6], acc[i][7]};
  }
  __syncthreads();

  // denominators + PV: v = l&31, half-wave splits k; shfl_xor(32) combines
  const int*   mrow = mask  + (size_t)n * T_ * V_;
  const float* vrow = value + (size_t)n * T_ * V_;
  int v = l & 31, kh = l >> 5;
  float s8[8], o8[8];
#pragma unroll
  for (int qq = 0; qq < 8; ++qq) { s8[qq] = 0.f; o8[qq] = 0.f; }
#pragma unroll 4
  for (int i = 0; i < 128; ++i) {
    int k = kh * 128 + i;
    float mf = (float)mrow[k * V_ + v];
    float vv = vrow[k * V_ + v];
    float4 e0 = *(const float4*)&e_s[k * 8];       // uniform per half-wave
    float4 e1 = *(const float4*)&e_s[k * 8 + 4];
    float p;
    p = e0.x * mf; s8[0] += p; o8[0] = fmaf(p, vv, o8[0]);
    p = e0.y * mf; s8[1] += p; o8[1] = fmaf(p, vv, o8[1]);
    p = e0.z * mf; s8[2] += p; o8[2] = fmaf(p, vv, o8[2]);
    p = e0.w * mf; s8[3] += p; o8[3] = fmaf(p, vv, o8[3]);
    p = e1.x * mf; s8[4] += p; o8[4] = fmaf(p, vv, o8[4]);
    p = e1.y * mf; s8[5] += p; o8[5] = fmaf(p, vv, o8[5]);
    p = e1.z * mf; s8[6] += p; o8[6] = fmaf(p, vv, o8[6]);
    p = e1.w * mf; s8[7] += p; o8[7] = fmaf(p, vv, o8[7]);
  }
#pragma unroll
  for (int qq = 0; qq < 8; ++qq) {
    s8[qq] += __shfl_xor(s8[qq], 32, 64);
    o8[qq] += __shfl_xor(o8[qq], 32, 64);
  }
  if (kh == 0) {
#pragma unroll
    for (int qq = 0; qq < 8; ++qq) {
      float inv = 1.0f / s8[qq];
      inv_s[qq * 32 + v] = inv;
      out_ws[(((size_t)n * T_ + q0 + qq) * H_ + h) * V_ + v] = o8[qq] * inv;
    }
  }
  __syncthreads();

  // direct p_attn streaming: 8 rows x 2048 f32x4, NT stores, coalesced per qq
  {
    int v0 = (l & 7) * 4;                 // e4&7 == l&7 for all reps
    f32x4 iv[8];
#pragma unroll
    for (int qq = 0; qq < 8; ++qq)
      iv[qq] = *(const f32x4*)&inv_s[qq * 32 + v0];
    f32x4* pbase = (f32x4*)p_out + (size_t)row0 * 2048;

#pragma unroll 4
    for (int rep = 0; rep < 32; ++rep) {
      int e4 = rep * 64 + l;
      int k  = rep * 8 + (l >> 3);
      const int4 m4 = *(const int4*)&mrow[k * V_ + v0];
      float fx = (float)m4.x, fy = (float)m4.y, fz = (float)m4.z, fw = (float)m4.w;
      f32x4 e0 = *(const f32x4*)&e_s[k * 8];
      f32x4 e1 = *(const f32x4*)&e_s[k * 8 + 4];
      float e[8] = {e0.x, e0.y, e0.z, e0.w, e1.x, e1.y, e1.z, e1.w};
#pragma unroll
      for (int qq = 0; qq < 8; ++qq) {
        f32x4 pv;
        pv.x = e[qq] * fx * iv[qq].x;
        pv.y = e[qq] * fy * iv[qq].y;
        pv.z = e[qq] * fz * iv[qq].z;
        pv.w = e[qq] * fw * iv[qq].w;
        __builtin_nontemporal_store(pv, &pbase[(size_t)qq * 2048 + e4]);
      }
    }
  }
}

// ---------------------------------------------------------------------------
// Phase 3 v2 (frozen from R8)
// ---------------------------------------------------------------------------
__global__ __launch_bounds__(256) void outproj_kernel(
    const float* __restrict__ out_ws, const float* __restrict__ Wo,
    const float* __restrict__ bo, float* __restrict__ out_rep)
{
  __shared__ float wot[256 * 33];
  __shared__ float rows_s[4 * 256];
  __shared__ float red[4 * 32];
  int r0 = blockIdx.x * 4;
  for (int i = threadIdx.x; i < 32 * 256; i += 256) {
    int o = i >> 8, c = i & 255;
    wot[c * 33 + o] = Wo[i];
  }
  for (int i = threadIdx.x; i < 4 * 256; i += 256)
    rows_s[i] = out_ws[(size_t)r0 * 256 + i];
  __syncthreads();
  int o  = threadIdx.x & 31;
  int rr = (threadIdx.x >> 5) & 3;
  int kh = threadIdx.x >> 7;
  int cb = kh * 128;
  float acc = 0.f;
#pragma unroll 4
  for (int c = 0; c < 128; ++c)
    acc = fmaf(rows_s[rr * 256 + cb + c], wot[(cb + c) * 33 + o], acc);
  if (kh == 1) red[rr * 32 + o] = acc;
  __syncthreads();
  if (kh == 0)
    out_rep[(size_t)(r0 + rr) * 32 + o] = acc + red[rr * 32 + o] + bo[o];
}

// ---------------------------------------------------------------------------
extern "C" void kernel_launch(void* const* d_in, const int* in_sizes, int n_in,
                              void* d_out, int out_size, void* d_ws, size_t ws_size,
                              hipStream_t stream) {
  const float* value = (const float*)d_in[0];
  const float* key   = (const float*)d_in[1];
  const float* query = (const float*)d_in[2];
  const int*   mask  = (const int*)d_in[3];
  const float* Wq = (const float*)d_in[4];
  const float* bq = (const float*)d_in[5];
  const float* Wk = (const float*)d_in[6];
  const float* bk = (const float*)d_in[7];
  const float* Wo = (const float*)d_in[8];
  const float* bo = (const float*)d_in[9];

  float* out_rep = (float*)d_out;
  float* p_out   = (float*)d_out + (size_t)N_ * T_ * V_;

  float* hqT    = (float*)d_ws;
  float* hkT    = hqT + (size_t)N_ * H_ * KQ_ * T_;
  float* out_ws = hkT + (size_t)N_ * H_ * KQ_ * T_;

  hipLaunchKernelGGL(proj_kernel, dim3(256), dim3(256), 0, stream,
                     query, key, Wq, bq, Wk, bk, hqT, hkT);
  hipLaunchKernelGGL(attn_kernel, dim3(2048), dim3(64), 0, stream,
                     hqT, hkT, mask, value, p_out, out_ws);
  hipLaunchKernelGGL(outproj_kernel, dim3(512), dim3(256), 0, stream,
                     out_ws, Wo, bo, out_rep);
}